// Round 8
// baseline (208.865 us; speedup 1.0000x reference)
//
#include <hip/hip_runtime.h>
#include <hip/hip_bf16.h>
#include <cstdint>
#include <cstddef>

#define IN_DIM 1024
#define OUT_DIM 1024
#define BATCH 2048
#define NSEG 8                    // surviving coefficients per input (m in [5,12])
#define K2 (IN_DIM * NSEG)        // 8192

#define BM 128
#define BN 256
#define BK 32
#define KSPLIT 8
#define KPB (K2 / KSPLIT)         // 1024
#define KSTEPS (KPB / BK)         // 32

typedef float f32x4 __attribute__((ext_vector_type(4)));
typedef __bf16 bf16x8 __attribute__((ext_vector_type(8)));

// round-to-nearest-even f32 -> bf16 bits (prep only)
__device__ __forceinline__ unsigned f2bf(float f) {
  unsigned u = __float_as_uint(f);
  u += 0x7FFF + ((u >> 16) & 1);
  return u >> 16;
}

// async global->LDS, 16B per lane (lds dest wave-uniform base + lane*16)
__device__ __forceinline__ void gload16(const void* g, void* l) {
  __builtin_amdgcn_global_load_lds((__attribute__((address_space(1))) void*)g,
                                   (__attribute__((address_space(3))) void*)l,
                                   16, 0, 0);
}

// quadratic B-spline 8-wide bf16 window, CHEAP version:
// 2x v_cvt_pk_bf16_f32 (1-inst pack of 2 bf16) + one 64-bit shift + cndmask
// placement. p = j-7 in [0,7] for x in [0,1); p>=8 degrades to zeros (no UB).
__device__ __forceinline__ uint4 basis8(float v) {
  float u = __builtin_fmaf(v, 1.0f / 0.15f, 7.5f);  // knots: -1.125 + m*0.15
  float jf = floorf(u);
  int j = (int)jf;                                   // 7..14
  float s = u - jf;
  float t1 = 1.f - s;
  float w0 = 0.5f * t1 * t1;
  float w1 = __builtin_fmaf(s, t1, 0.5f);
  float w2 = 0.5f * s * s;
  unsigned d0, d1;
  asm("v_cvt_pk_bf16_f32 %0, %1, %2" : "=v"(d0) : "v"(w0), "v"(w1));
  asm("v_cvt_pk_bf16_f32 %0, %1, %2" : "=v"(d1) : "v"(w2), "v"(0.f));
  int p = j - 7;
  unsigned long long full = (((unsigned long long)d1 << 32) | d0) << ((p & 1) << 4);
  unsigned lo = (unsigned)full, hi = (unsigned)(full >> 32);
  int q = p >> 1;
  uint4 o;
  o.x = q == 0 ? lo : 0u;
  o.y = q == 1 ? lo : (q == 0 ? hi : 0u);
  o.z = q == 2 ? lo : (q == 1 ? hi : 0u);
  o.w = q == 3 ? lo : (q == 2 ? hi : 0u);
  return o;
}

// ---------------------------------------------------------------------------
// prep (merged): blocks [0,4096) repack P coeffs 5..12 * w_s -> bf16 B'
// (LDS-coalesced); blocks [4096,6144) compute out[b][:] = w_b * silu-rowsum.
// ---------------------------------------------------------------------------
__global__ __launch_bounds__(256) void prep(const float* __restrict__ p,
                                            const float* __restrict__ x,
                                            short* __restrict__ B,
                                            float* __restrict__ out,
                                            const float* __restrict__ wbp,
                                            const float* __restrict__ wsp) {
  __shared__ float ld[3328];
  const int blk = blockIdx.x;
  const int t = threadIdx.x;
  if (blk < 4096) {
    const uint4* src = (const uint4*)(p + (size_t)blk * 3328);   // 832 uint4
    uint4* l4 = (uint4*)ld;
#pragma unroll
    for (int c = 0; c < 3; ++c) l4[c * 256 + t] = src[c * 256 + t];
    if (t < 64) l4[768 + t] = src[768 + t];
    __syncthreads();
    const float* my = ld + t * 13 + 5;   // stride 13 dwords: conflict-free
    const float w = wsp[0];
    uint4 o;
    o.x = f2bf(w * my[0]) | (f2bf(w * my[1]) << 16);
    o.y = f2bf(w * my[2]) | (f2bf(w * my[3]) << 16);
    o.z = f2bf(w * my[4]) | (f2bf(w * my[5]) << 16);
    o.w = f2bf(w * my[6]) | (f2bf(w * my[7]) << 16);
    ((uint4*)B)[(size_t)blk * 256 + t] = o;
  } else {
    const int b = blk - 4096;
    float4 xv = ((const float4*)(x + (size_t)b * IN_DIM))[t];
    float lsum = xv.x / (1.f + __expf(-xv.x)) + xv.y / (1.f + __expf(-xv.y)) +
                 xv.z / (1.f + __expf(-xv.z)) + xv.w / (1.f + __expf(-xv.w));
#pragma unroll
    for (int off = 32; off >= 1; off >>= 1) lsum += __shfl_down(lsum, off);
    if ((t & 63) == 0) ld[t >> 6] = lsum;
    __syncthreads();
    float v = wbp[0] * (ld[0] + ld[1] + ld[2] + ld[3]);
    float4 vv = {v, v, v, v};
    ((float4*)(out + (size_t)b * OUT_DIM))[t] = vv;
  }
}

// ---------------------------------------------------------------------------
// gemm_fused: out += bases(x)(2048x8192) * B'(1024x8192)^T.
// 128x256 tile, BK=32, 512 threads (8 waves, 2x4; wave tile 64x64 = 4x4 mfma).
// Pipeline: Bs[3] lookahead-2 via global_load_lds; As[2] basis-on-the-fly.
// Per step exactly 3 VMEM issue (2 B-stage + 1 x) -> pre-barrier vmcnt(3)
// guarantees B(t+1) (and everything older) landed before ANY wave crosses the
// barrier; B(t+2)+x stay in flight across it. lgkmcnt(0)+raw s_barrier covers
// the cross-wave As/Bs LDS writes. Prologue drains vmcnt(0) once (order-safe).
// Grid 512 1-D, XCD-aware decode: ks=bid&7, bm=(bid>>3)&15, bn=bid>>7 ->
// each XCD's resident B-slices = 2 MB <= 4 MB L2.
// split-K=8 atomic epilogue (w_s folded into B').
// ---------------------------------------------------------------------------
__global__ __launch_bounds__(512) void gemm_fused(const float* __restrict__ x,
                                                  const short* __restrict__ B,
                                                  float* __restrict__ out) {
  __shared__ __bf16 As[2][BM][BK];   // 16 KB
  __shared__ __bf16 Bs[3][BN][BK];   // 48 KB

  const int tid = threadIdx.x;
  const int wid = tid >> 6;          // 0..7
  const int lane = tid & 63;
  const int bid = blockIdx.x;
  const int ks = bid & 7;
  const int bm = (bid >> 3) & 15;
  const int bn = bid >> 7;
  const int row0 = bm * BM;
  const int col0 = bn * BN;
  const int kstart = ks * KPB;
  const int istart = kstart / NSEG;

  // B staging: wave wid stages Bs rows [32*wid, 32*wid+32) (2 insts/step);
  // it CONSUMES rows [64*(wid&3), +64) -> cross-wave halves, covered by the
  // pre-barrier vmcnt discipline (every wave drains its B(t+1) before the
  // barrier, so after the barrier all halves are visible).
  const short* bg = B + (size_t)(col0 + 32 * wid + (lane >> 2)) * K2 + kstart +
                    (lane & 3) * 8;

  // A on-the-fly: thread t -> (row t>>2, window-input t&3); uint4 slot t.
  const float* xp = x + (size_t)(row0 + (tid >> 2)) * IN_DIM + istart + (tid & 3);

  f32x4 acc[4][4];
#pragma unroll
  for (int m = 0; m < 4; ++m)
#pragma unroll
    for (int n = 0; n < 4; ++n) acc[m][n] = (f32x4){0.f, 0.f, 0.f, 0.f};

  const int wr = (wid >> 2) * 64;    // wave row offset (0/64)
  const int wc = (wid & 3) * 64;     // wave col offset (0/64/128/192)
  const int fr = lane & 15;
  const int fk = (lane >> 4) * 8;

#define STAGE_B(kt_, buf_)                                                    \
  {                                                                           \
    const int kb_ = (kt_)*BK;                                                 \
    gload16(bg + kb_, &Bs[buf_][32 * wid][0]);                                \
    gload16(bg + (size_t)16 * K2 + kb_, &Bs[buf_][32 * wid + 16][0]);         \
  }

#define COMPUTE(A_, B_)                                                       \
  {                                                                           \
    bf16x8 af_[4], bb_[4];                                                    \
    _Pragma("unroll") for (int m_ = 0; m_ < 4; ++m_)                          \
        af_[m_] = *(const bf16x8*)&(A_)[wr + m_ * 16 + fr][fk];               \
    _Pragma("unroll") for (int n_ = 0; n_ < 4; ++n_)                          \
        bb_[n_] = *(const bf16x8*)&(B_)[wc + n_ * 16 + fr][fk];               \
    _Pragma("unroll") for (int m_ = 0; m_ < 4; ++m_)                          \
        _Pragma("unroll") for (int n_ = 0; n_ < 4; ++n_)                      \
            acc[m_][n_] = __builtin_amdgcn_mfma_f32_16x16x32_bf16(            \
                af_[m_], bb_[n_], acc[m_][n_], 0, 0, 0);                      \
  }

#define LDS_BARRIER                                                           \
  asm volatile("s_waitcnt lgkmcnt(0)" ::: "memory");                          \
  __builtin_amdgcn_s_barrier();

  // ---- prologue: stage B(0),B(1); basis(0); full drain once ----
  float xc = xp[0];
  STAGE_B(0, 0);
  STAGE_B(1, 1);
  float xn0 = xp[4];                 // x(1)
  float xn1 = xp[8];                 // x(2)
  ((uint4*)As[0])[tid] = basis8(xc);
  asm volatile("s_waitcnt vmcnt(0)" ::: "memory");
  LDS_BARRIER;

  // ---- main: t = 0..29, 6-unrolled (all buffer indices compile-time) ----
  float xnew;
#define STEP(s_)                                                              \
  {                                                                           \
    const int t_ = 6 * i + (s_);                                              \
    STAGE_B(t_ + 2, ((s_) + 2) % 3);                                          \
    ((uint4*)As[((s_) + 1) & 1])[tid] = basis8(xn0);                          \
    { int tn_ = t_ + 3; tn_ = tn_ > 31 ? 31 : tn_; xnew = xp[tn_ * 4]; }      \
    COMPUTE(As[(s_) & 1], Bs[(s_) % 3]);                                      \
    asm volatile("s_waitcnt vmcnt(3)" ::: "memory");                          \
    LDS_BARRIER;                                                              \
    xn0 = xn1; xn1 = xnew;                                                    \
  }

#pragma unroll 1
  for (int i = 0; i < 5; ++i) {
    STEP(0) STEP(1) STEP(2) STEP(3) STEP(4) STEP(5)
  }

  // ---- tail: t=30 (basis(31), compute(30)), then t=31 ----
  ((uint4*)As[1])[tid] = basis8(xn0);          // xn0 = x(31)
  COMPUTE(As[0], Bs[0]);                       // t=30: 30&1=0, 30%3=0
  asm volatile("s_waitcnt vmcnt(0)" ::: "memory");
  LDS_BARRIER;
  COMPUTE(As[1], Bs[1]);                       // t=31: 31&1=1, 31%3=1

#undef STEP
#undef STAGE_B
#undef COMPUTE
#undef LDS_BARRIER

  // epilogue: C/D layout col=lane&15, row=(lane>>4)*4+reg (w_s folded in B')
  const int orow = (lane >> 4) * 4;
#pragma unroll
  for (int m = 0; m < 4; ++m)
#pragma unroll
    for (int n = 0; n < 4; ++n) {
      const int rg = row0 + wr + m * 16 + orow;
      const int cg = col0 + wc + n * 16 + fr;
      float* op = out + (size_t)rg * OUT_DIM + cg;
#pragma unroll
      for (int r = 0; r < 4; ++r)
        atomicAdd(op + (size_t)r * OUT_DIM, acc[m][n][r]);
    }
}

// ---------------------------------------------------------------------------
extern "C" void kernel_launch(void* const* d_in, const int* in_sizes, int n_in,
                              void* d_out, int out_size, void* d_ws, size_t ws_size,
                              hipStream_t stream) {
  const float* x = (const float*)d_in[0];     // [2048][1024]
  const float* p = (const float*)d_in[1];     // [1024][1024][13]
  const float* wb = (const float*)d_in[2];    // scalar
  const float* wsc = (const float*)d_in[3];   // scalar
  float* out = (float*)d_out;                 // [2048][1024] fp32

  short* B = (short*)d_ws;                    // B' bf16: 16,777,216 B

  prep<<<6144, 256, 0, stream>>>(p, x, B, out, wb, wsc);
  gemm_fused<<<512, 512, 0, stream>>>(x, B, out);
}

// Round 12
// 184.299 us; speedup vs baseline: 1.1333x; 1.1333x over previous
//
#include <hip/hip_runtime.h>
#include <hip/hip_bf16.h>
#include <cstdint>
#include <cstddef>

#define IN_DIM 1024
#define OUT_DIM 1024
#define BATCH 2048
#define NSEG 8                    // surviving coefficients per input (m in [5,12])
#define K2 (IN_DIM * NSEG)        // 8192

#define BM 64
#define BN 256
#define BK 32
#define KSPLIT 8
#define KPB (K2 / KSPLIT)         // 1024
#define KSTEPS (KPB / BK)         // 32

typedef float f32x4 __attribute__((ext_vector_type(4)));
typedef __bf16 bf16x8 __attribute__((ext_vector_type(8)));

// round-to-nearest-even f32 -> bf16 bits (prep only)
__device__ __forceinline__ unsigned f2bf(float f) {
  unsigned u = __float_as_uint(f);
  u += 0x7FFF + ((u >> 16) & 1);
  return u >> 16;
}

// async global->LDS, 16B per lane (lds dest wave-uniform base + lane*16)
__device__ __forceinline__ void gload16(const void* g, void* l) {
  __builtin_amdgcn_global_load_lds((__attribute__((address_space(1))) void*)g,
                                   (__attribute__((address_space(3))) void*)l,
                                   16, 0, 0);
}

// quadratic B-spline 8-wide bf16 window, CHEAP version (proven R8: -50% VALU):
// 2x v_cvt_pk_bf16_f32 + one 64-bit shift + cndmask placement.
__device__ __forceinline__ uint4 basis8(float v) {
  float u = __builtin_fmaf(v, 1.0f / 0.15f, 7.5f);  // knots: -1.125 + m*0.15
  float jf = floorf(u);
  int j = (int)jf;                                   // 7..14 for x in [0,1)
  float s = u - jf;
  float t1 = 1.f - s;
  float w0 = 0.5f * t1 * t1;
  float w1 = __builtin_fmaf(s, t1, 0.5f);
  float w2 = 0.5f * s * s;
  unsigned d0, d1;
  asm("v_cvt_pk_bf16_f32 %0, %1, %2" : "=v"(d0) : "v"(w0), "v"(w1));
  asm("v_cvt_pk_bf16_f32 %0, %1, %2" : "=v"(d1) : "v"(w2), "v"(0.f));
  int p = j - 7;
  unsigned long long full = (((unsigned long long)d1 << 32) | d0) << ((p & 1) << 4);
  unsigned lo = (unsigned)full, hi = (unsigned)(full >> 32);
  int q = p >> 1;
  uint4 o;
  o.x = q == 0 ? lo : 0u;
  o.y = q == 1 ? lo : (q == 0 ? hi : 0u);
  o.z = q == 2 ? lo : (q == 1 ? hi : 0u);
  o.w = q == 3 ? lo : (q == 2 ? hi : 0u);
  return o;
}

// ---------------------------------------------------------------------------
// prep (merged): blocks [0,4096) repack P coeffs 5..12 * w_s -> bf16 B'
// (LDS-coalesced); blocks [4096,6144) compute out[b][:] = w_b * silu-rowsum.
// ---------------------------------------------------------------------------
__global__ __launch_bounds__(256) void prep(const float* __restrict__ p,
                                            const float* __restrict__ x,
                                            short* __restrict__ B,
                                            float* __restrict__ out,
                                            const float* __restrict__ wbp,
                                            const float* __restrict__ wsp) {
  __shared__ float ld[3328];
  const int blk = blockIdx.x;
  const int t = threadIdx.x;
  if (blk < 4096) {
    const uint4* src = (const uint4*)(p + (size_t)blk * 3328);   // 832 uint4
    uint4* l4 = (uint4*)ld;
#pragma unroll
    for (int c = 0; c < 3; ++c) l4[c * 256 + t] = src[c * 256 + t];
    if (t < 64) l4[768 + t] = src[768 + t];
    __syncthreads();
    const float* my = ld + t * 13 + 5;   // stride 13 dwords: conflict-free
    const float w = wsp[0];
    uint4 o;
    o.x = f2bf(w * my[0]) | (f2bf(w * my[1]) << 16);
    o.y = f2bf(w * my[2]) | (f2bf(w * my[3]) << 16);
    o.z = f2bf(w * my[4]) | (f2bf(w * my[5]) << 16);
    o.w = f2bf(w * my[6]) | (f2bf(w * my[7]) << 16);
    ((uint4*)B)[(size_t)blk * 256 + t] = o;
  } else {
    const int b = blk - 4096;
    float4 xv = ((const float4*)(x + (size_t)b * IN_DIM))[t];
    float lsum = xv.x / (1.f + __expf(-xv.x)) + xv.y / (1.f + __expf(-xv.y)) +
                 xv.z / (1.f + __expf(-xv.z)) + xv.w / (1.f + __expf(-xv.w));
#pragma unroll
    for (int off = 32; off >= 1; off >>= 1) lsum += __shfl_down(lsum, off);
    if ((t & 63) == 0) ld[t >> 6] = lsum;
    __syncthreads();
    float v = wbp[0] * (ld[0] + ld[1] + ld[2] + ld[3]);
    float4 vv = {v, v, v, v};
    ((float4*)(out + (size_t)b * OUT_DIM))[t] = vv;
  }
}

// ---------------------------------------------------------------------------
// gemm_fused: out += bases(x)(2048x8192) * B'(1024x8192)^T.
// R6 structure: 64x256 tile, BK=32, 4 waves (each 64x64), counted-vmcnt
// pipeline: each wave stages AND consumes its own 64 Bs rows (sync = per-wave
// vmcnt(5), loads span iterations); cross-wave As syncs via the fenced
// barrier below; vmcnt is NEVER drained at the barrier.
// RACE FIX (R10 post-timing divergence): raw s_barrier is IntrNoMem in LLVM,
// so LDS reads after it could be HOISTED ABOVE the barrier (reading As before
// other waves wrote it). The barrier must be fenced on BOTH sides:
//   asm lgkmcnt(0)+memory  |  s_barrier  |  asm ""+memory + sched_barrier(0)
// KSPLIT=8 -> grid 1024 = 4 blocks/CU (LDS 40KB x4 = 160KB);
// XCD decode ks=bid&7 -> each XCD owns one K-slice: B' 2MB + x 1MB L2-hot.
// split-K atomic epilogue (w_s folded into B').
// ---------------------------------------------------------------------------
__global__ __launch_bounds__(256) void gemm_fused(const float* __restrict__ x,
                                                  const short* __restrict__ B,
                                                  float* __restrict__ out) {
  __shared__ __bf16 As[2][BM][BK];   //  8 KB
  __shared__ __bf16 Bs[2][BN][BK];   // 32 KB

  const int tid = threadIdx.x;
  const int wid = tid >> 6;
  const int lane = tid & 63;
  const int bid = blockIdx.x;
  const int ks = bid & 7;            // XCD-aware: consecutive bids span XCDs
  const int bm = (bid >> 3) & 31;    // 32 M-tiles
  const int bn = bid >> 8;           // 4 N-tiles
  const int row0 = bm * BM;
  const int col0 = bn * BN;
  const int kstart = ks * KPB;
  const int istart = kstart / NSEG;  // ks*128

  // B staging: wave wid stages AND consumes rows [64*wid, 64*wid+64)
  const int sr = lane >> 2;
  const int sc = (lane & 3) * 8;
  const short* bg = B + (size_t)(col0 + 64 * wid + sr) * K2 + kstart + sc;

  // A on-the-fly: thread t -> (row t>>2, input t&3); uint4 slot t (lane-linear)
  const float* xp = x + (size_t)(row0 + (tid >> 2)) * IN_DIM + istart + (tid & 3);

  f32x4 acc[4][4];
#pragma unroll
  for (int m = 0; m < 4; ++m)
#pragma unroll
    for (int n = 0; n < 4; ++n) acc[m][n] = (f32x4){0.f, 0.f, 0.f, 0.f};

  const int wc = 64 * wid;
  const int fr = lane & 15;
  const int fk = (lane >> 4) * 8;

#define STAGE_B(kt_, buf_)                                                    \
  {                                                                           \
    const int kb_ = (kt_)*BK;                                                 \
    _Pragma("unroll") for (int c = 0; c < 4; ++c)                             \
        gload16(bg + (size_t)(c * 16) * K2 + kb_,                             \
                &Bs[buf_][64 * wid + c * 16][0]);                             \
  }

#define COMPUTE(buf_)                                                         \
  {                                                                           \
    bf16x8 af[4], bb[4];                                                      \
    _Pragma("unroll") for (int m = 0; m < 4; ++m)                             \
        af[m] = *(const bf16x8*)&As[buf_][m * 16 + fr][fk];                   \
    _Pragma("unroll") for (int n = 0; n < 4; ++n)                             \
        bb[n] = *(const bf16x8*)&Bs[buf_][wc + n * 16 + fr][fk];              \
    _Pragma("unroll") for (int m = 0; m < 4; ++m)                             \
        _Pragma("unroll") for (int n = 0; n < 4; ++n)                         \
            acc[m][n] = __builtin_amdgcn_mfma_f32_16x16x32_bf16(              \
                af[m], bb[n], acc[m][n], 0, 0, 0);                            \
  }

// Two-sided fenced workgroup barrier that does NOT drain vmcnt.
// Pre-side: lgkmcnt(0) with memory clobber (own ds ops retired, no sinking).
// Post-side: empty memory-clobber asm + sched_barrier(0) (no LDS access may
// hoist above the s_barrier -- IR and MIR level).
#define LDS_BARRIER                                                           \
  asm volatile("s_waitcnt lgkmcnt(0)" ::: "memory");                          \
  __builtin_amdgcn_s_barrier();                                               \
  asm volatile("" ::: "memory");                                              \
  __builtin_amdgcn_sched_barrier(0);

  // ---- prologue: stage tile 0 into buffer 0 ----
  float xa = xp[0];                  // x(0)
  float xb = xp[4];                  // x(1)
  STAGE_B(0, 0);
  ((uint4*)As[0])[tid] = basis8(xa);
  LDS_BARRIER;                       // As(0) visible; B(0) still in flight

  // ---- main loop: t = 0..29, 2x-unrolled (15 pairs) ----
#pragma unroll 1
  for (int i = 0; i < (KSTEPS - 2) / 2; ++i) {
    const int t0 = 2 * i;
    // even step t0: stage t0+1 (odd -> uses xb), reload xa = x(t0+2)
    STAGE_B(t0 + 1, 1);
    ((uint4*)As[1])[tid] = basis8(xb);
    xa = xp[(t0 + 2) * 4];
    asm volatile("s_waitcnt vmcnt(5)" ::: "memory");  // B(t0) done; B(t0+1)+x fly
    COMPUTE(0);
    LDS_BARRIER;
    // odd step t0+1: stage t0+2 (even -> uses xa), reload xb = x(t0+3)
    STAGE_B(t0 + 2, 0);
    ((uint4*)As[0])[tid] = basis8(xa);
    xb = xp[(t0 + 3) * 4];
    asm volatile("s_waitcnt vmcnt(5)" ::: "memory");
    COMPUTE(1);
    LDS_BARRIER;
  }

  // ---- peeled tail: t = 30 (stage 31), then t = 31 ----
  STAGE_B(KSTEPS - 1, 1);            // tile 31 -> buf 1; uses xb = x(31)
  ((uint4*)As[1])[tid] = basis8(xb);
  asm volatile("s_waitcnt vmcnt(4)" ::: "memory");   // B(30) done
  COMPUTE(0);
  LDS_BARRIER;

  asm volatile("s_waitcnt vmcnt(0)" ::: "memory");   // B(31) done
  COMPUTE(1);

#undef STAGE_B
#undef COMPUTE
#undef LDS_BARRIER

  // epilogue: C/D layout col=lane&15, row=(lane>>4)*4+reg (w_s folded into B')
  const int orow = (lane >> 4) * 4;
#pragma unroll
  for (int m = 0; m < 4; ++m)
#pragma unroll
    for (int n = 0; n < 4; ++n) {
      const int rg = row0 + m * 16 + orow;
      const int cg = col0 + wc + n * 16 + fr;
      float* op = out + (size_t)rg * OUT_DIM + cg;
#pragma unroll
      for (int r = 0; r < 4; ++r)
        atomicAdd(op + (size_t)r * OUT_DIM, acc[m][n][r]);
    }
}

// ---------------------------------------------------------------------------
extern "C" void kernel_launch(void* const* d_in, const int* in_sizes, int n_in,
                              void* d_out, int out_size, void* d_ws, size_t ws_size,
                              hipStream_t stream) {
  const float* x = (const float*)d_in[0];     // [2048][1024]
  const float* p = (const float*)d_in[1];     // [1024][1024][13]
  const float* wb = (const float*)d_in[2];    // scalar
  const float* wsc = (const float*)d_in[3];   // scalar
  float* out = (float*)d_out;                 // [2048][1024] fp32

  short* B = (short*)d_ws;                    // B' bf16: 16,777,216 B

  prep<<<6144, 256, 0, stream>>>(p, x, B, out, wb, wsc);
  gemm_fused<<<1024, 256, 0, stream>>>(x, B, out);
}